// Round 24
// baseline (531.677 us; speedup 1.0000x reference)
//
#include <hip/hip_runtime.h>
#include <hip/hip_bf16.h>

#define HDIM 4096
#define EDIM 64
#define NW   8            // waves per block
#define EPW  8            // experts per wave (8 waves x 8 = 64)
#define BH   64           // h-chunk
#define NCH  (HDIM/BH)    // 64 chunks
#define LDW  (BH + 1)     // stride 65: 2-way banks = free

typedef float f32x4 __attribute__((ext_vector_type(4)));

// Semantics (locked r16): inputs f32-backed bf16; logit = np-einsum-SSE
// 4-chain f32 mul/add (NO FMA), groups of 8 ascending h, (l0+l1)+(l2+l3),
// bf16-round, f32 routing, f32 out [idx 4T | w 4T | k T].
// r24 FLIP: lane=token, wave=8 experts. Hidden global->LDS->VGPR (reused 8x);
// weight wave-uniform s_load. Chain per (t,e) stays on one lane, order exact.
__global__ __launch_bounds__(512) void router_flip(
    const float* __restrict__ hidden,
    const float* __restrict__ weight,
    float* __restrict__ out,
    int T)
{
    __shared__ float hlds[2][EDIM][LDW];   // 64 tokens x 64-word chunk, dbuf (33 KB)
    __shared__ float lg[EDIM][LDW];        // 64 tokens x 64 expert logits (17 KB)

    const int tid   = threadIdx.x;
    const int lane  = tid & 63;
    const int wv    = tid >> 6;            // 0..7
    const int ebase = wv * EPW;
    const int t0    = blockIdx.x * 64;

    // staging: thread -> (token row tid>>3, 8-word seg (tid&7)*8); coalesced 256B/8thr
    const int srow = tid >> 3;
    const int sq   = (tid & 7) * 8;
    const float* hbase = hidden + (size_t)(t0 + srow) * HDIM + sq;

    float acc[EPW][4];
#pragma unroll
    for (int e = 0; e < EPW; ++e)
        { acc[e][0]=0.f; acc[e][1]=0.f; acc[e][2]=0.f; acc[e][3]=0.f; }

    // prologue: stage chunk 0
    {
        f32x4 v0 = *reinterpret_cast<const f32x4*>(hbase);
        f32x4 v1 = *reinterpret_cast<const f32x4*>(hbase + 4);
        hlds[0][srow][sq+0]=v0.x; hlds[0][srow][sq+1]=v0.y;
        hlds[0][srow][sq+2]=v0.z; hlds[0][srow][sq+3]=v0.w;
        hlds[0][srow][sq+4]=v1.x; hlds[0][srow][sq+5]=v1.y;
        hlds[0][srow][sq+6]=v1.z; hlds[0][srow][sq+7]=v1.w;
    }
    __syncthreads();

    for (int c = 0; c < NCH; ++c) {
        const int cur = c & 1;
        if (c + 1 < NCH) {
            const float* hp = hbase + (c + 1) * BH;
            f32x4 v0 = *reinterpret_cast<const f32x4*>(hp);
            f32x4 v1 = *reinterpret_cast<const f32x4*>(hp + 4);
            hlds[cur^1][srow][sq+0]=v0.x; hlds[cur^1][srow][sq+1]=v0.y;
            hlds[cur^1][srow][sq+2]=v0.z; hlds[cur^1][srow][sq+3]=v0.w;
            hlds[cur^1][srow][sq+4]=v1.x; hlds[cur^1][srow][sq+5]=v1.y;
            hlds[cur^1][srow][sq+6]=v1.z; hlds[cur^1][srow][sq+7]=v1.w;
        }

        // my token's chunk -> VGPRs (read once, reused by all 8 experts)
        float hv[BH];
#pragma unroll
        for (int j = 0; j < BH; ++j) hv[j] = hlds[cur][lane][j];

#pragma unroll
        for (int e = 0; e < EPW; ++e) {
            // wave-uniform weight row chunk -> s_load path
            const float* wrow = weight + (size_t)(ebase + e) * HDIM + (size_t)c * BH;
#pragma unroll
            for (int g = 0; g < BH / 8; ++g) {
                acc[e][0] = __fadd_rn(acc[e][0], __fmul_rn(hv[g*8+0], wrow[g*8+0]));
                acc[e][1] = __fadd_rn(acc[e][1], __fmul_rn(hv[g*8+1], wrow[g*8+1]));
                acc[e][2] = __fadd_rn(acc[e][2], __fmul_rn(hv[g*8+2], wrow[g*8+2]));
                acc[e][3] = __fadd_rn(acc[e][3], __fmul_rn(hv[g*8+3], wrow[g*8+3]));
                acc[e][0] = __fadd_rn(acc[e][0], __fmul_rn(hv[g*8+4], wrow[g*8+4]));
                acc[e][1] = __fadd_rn(acc[e][1], __fmul_rn(hv[g*8+5], wrow[g*8+5]));
                acc[e][2] = __fadd_rn(acc[e][2], __fmul_rn(hv[g*8+6], wrow[g*8+6]));
                acc[e][3] = __fadd_rn(acc[e][3], __fmul_rn(hv[g*8+7], wrow[g*8+7]));
            }
        }
        __syncthreads();
    }

    // ---- logits to LDS (bf16-rounded), then per-wave routing of 8 tokens ----
#pragma unroll
    for (int e = 0; e < EPW; ++e) {
        const float a = __fadd_rn(__fadd_rn(acc[e][0], acc[e][1]),
                                  __fadd_rn(acc[e][2], acc[e][3]));
        lg[lane][ebase + e] = __bfloat162float(__float2bfloat16(a));
    }
    __syncthreads();

    const size_t T4 = (size_t)T * 4;

#pragma unroll 1
    for (int s = 0; s < 8; ++s) {
        const int tt = wv * 8 + s;          // token slot within block
        const float lv = lg[tt][lane];      // lane = expert now

        float mx = lv;
#pragma unroll
        for (int d = 1; d < 64; d <<= 1) mx = fmaxf(mx, __shfl_xor(mx, d));
        const float ev = expf(lv - mx);
        float ssum = ev;
#pragma unroll
        for (int d = 1; d < 64; d <<= 1) ssum += __shfl_xor(ssum, d);
        const float p = ev / ssum;

        float ent = p * logf(p + 1e-9f);
#pragma unroll
        for (int d = 1; d < 64; d <<= 1) ent += __shfl_xor(ent, d);
        const float Hent = -ent;

        float pv[4]; int pi[4];
        float cand = p;
#pragma unroll
        for (int r = 0; r < 4; ++r) {
            float bv = cand; int bi = lane;
#pragma unroll
            for (int d = 1; d < 64; d <<= 1) {
                float ov = __shfl_xor(bv, d);
                int   oi = __shfl_xor(bi, d);
                if (ov > bv || (ov == bv && oi < bi)) { bv = ov; bi = oi; }
            }
            pv[r] = bv; pi[r] = bi;
            if (lane == bi) cand = -1.f;
        }

        const int kk = (Hent < 0.3f) ? 1 : (Hent > 1.5f) ? 4 : 2;

        float wsum = 0.f;
#pragma unroll
        for (int r = 0; r < 4; ++r) if (r < kk) wsum += pv[r];

        if (lane == 0) {
            const size_t gt = (size_t)(t0 + tt);
#pragma unroll
            for (int r = 0; r < 4; ++r) {
                out[gt * 4 + r]      = (r < kk) ? (float)pi[r] : -1.f;
                out[T4 + gt * 4 + r] = (r < kk) ? pv[r] / wsum : 0.f;
            }
            out[2 * T4 + gt] = (float)kk;
        }
    }
}

extern "C" void kernel_launch(void* const* d_in, const int* in_sizes, int n_in,
                              void* d_out, int out_size, void* d_ws, size_t ws_size,
                              hipStream_t stream) {
    const float* hidden = (const float*)d_in[0];
    const float* weight = (const float*)d_in[1];
    float* out = (float*)d_out;
    const int T = in_sizes[0] / HDIM;      // 16384
    const int blocks = T / 64;             // 256
    hipLaunchKernelGGL(router_flip, dim3(blocks), dim3(512), 0, stream,
                       hidden, weight, out, T);
}